// Round 1
// baseline (1789.016 us; speedup 1.0000x reference)
//
#include <hip/hip_runtime.h>

// GCN 3-layer + JK-concat.  N=100000 nodes, E=1600000 edges, F_IN=128, H=64, F_OUT=64.
//
// Algebra: out[d] = dis[d] * sum_{s in N(d) U {d}} dis[s]*(h@W)[s]  + b
//   k_gemm_scale : u = (h @ W) * dis[row]   (also acc = u  -> self-loop contribution)
//   k_scatter    : acc[dst] += u[src]  over E real edges (atomicAdd, lane=feature)
//   k_relu       : h_next = relu(acc * dis[row] + b)
// Final: out = concat(x,h1,h2,h3) @ Wl + bl, done as two LDS-staged passes.

#define N_NODES 100000
#define N_EDGES 1600000
#define F_IN    128
#define HID     64

// ---------------- degree / normalization ----------------
__global__ void k_deg_init(float* __restrict__ deg) {
    int i = blockIdx.x * blockDim.x + threadIdx.x;
    if (i < N_NODES) deg[i] = 1.0f;   // self-loop
}

__global__ void k_deg_accum(const int* __restrict__ dst, float* __restrict__ deg) {
    int stride = gridDim.x * blockDim.x;
    for (int e = blockIdx.x * blockDim.x + threadIdx.x; e < N_EDGES; e += stride)
        atomicAdd(&deg[dst[e]], 1.0f);
}

__global__ void k_dis(float* __restrict__ deg) {
    int i = blockIdx.x * blockDim.x + threadIdx.x;
    if (i < N_NODES) deg[i] = rsqrtf(deg[i]);   // deg >= 1 always
}

// ---------------- per-layer GEMM + dis-scale ----------------
// u[row, j] = (sum_k h[row,k] * W[k,j]) * dis[row];  acc = u (self loop)
template<int K>
__global__ __launch_bounds__(256) void k_gemm_scale(
        const float* __restrict__ h, const float* __restrict__ W,
        const float* __restrict__ dis, float* __restrict__ u, float* __restrict__ acc) {
    __shared__ float Ws[K * HID];
    for (int i = threadIdx.x; i < K * HID; i += blockDim.x) Ws[i] = W[i];
    __syncthreads();
    const int lane = threadIdx.x & 63;
    const int rg   = threadIdx.x >> 6;
    const int rpb  = blockDim.x >> 6;            // rows per block per iter (4)
    for (int row = blockIdx.x * rpb + rg; row < N_NODES; row += gridDim.x * rpb) {
        const float* hr = h + (size_t)row * K;
        float a = 0.f;
        #pragma unroll 8
        for (int k4 = 0; k4 < K; k4 += 4) {
            float4 hv = *reinterpret_cast<const float4*>(hr + k4);
            a = fmaf(hv.x, Ws[(k4 + 0) * HID + lane], a);
            a = fmaf(hv.y, Ws[(k4 + 1) * HID + lane], a);
            a = fmaf(hv.z, Ws[(k4 + 2) * HID + lane], a);
            a = fmaf(hv.w, Ws[(k4 + 3) * HID + lane], a);
        }
        a *= dis[row];
        int o = row * HID + lane;
        u[o] = a;
        acc[o] = a;
    }
}

// ---------------- edge scatter: acc[dst] += u[src] ----------------
// one wave (64 lanes) per edge, lane = feature -> coalesced 256B gather + 64 dword atomics
__global__ __launch_bounds__(256) void k_scatter(
        const int* __restrict__ src, const int* __restrict__ dst,
        const float* __restrict__ u, float* __restrict__ acc) {
    const long long total  = (long long)N_EDGES * HID;
    const long long stride = (long long)gridDim.x * blockDim.x;
    for (long long t = (long long)blockIdx.x * blockDim.x + threadIdx.x; t < total; t += stride) {
        int e = (int)(t >> 6);
        int j = (int)t & 63;
        int s = src[e];         // wave-uniform
        int d = dst[e];         // wave-uniform
        atomicAdd(&acc[d * HID + j], u[s * HID + j]);
    }
}

// ---------------- epilogue: h = relu(acc*dis + b) ----------------
__global__ void k_relu(const float* __restrict__ acc, const float* __restrict__ dis,
                       const float* __restrict__ b, float* __restrict__ h) {
    const int total  = N_NODES * HID;
    const int stride = gridDim.x * blockDim.x;
    for (int t = blockIdx.x * blockDim.x + threadIdx.x; t < total; t += stride) {
        int row = t >> 6, j = t & 63;
        float v = fmaf(acc[t], dis[row], b[j]);
        h[t] = v > 0.f ? v : 0.f;
    }
}

// ---------------- final linear, pass A: out = bl + x @ Wl[0:128] ----------------
__global__ __launch_bounds__(256) void k_linA(
        const float* __restrict__ x, const float* __restrict__ Wl,
        const float* __restrict__ bl, float* __restrict__ out) {
    __shared__ float Ws[F_IN * HID];   // 32 KB
    for (int i = threadIdx.x; i < F_IN * HID; i += blockDim.x) Ws[i] = Wl[i];
    __syncthreads();
    const int lane = threadIdx.x & 63, rg = threadIdx.x >> 6, rpb = blockDim.x >> 6;
    for (int row = blockIdx.x * rpb + rg; row < N_NODES; row += gridDim.x * rpb) {
        const float* xr = x + (size_t)row * F_IN;
        float a = bl[lane];
        #pragma unroll 8
        for (int k4 = 0; k4 < F_IN; k4 += 4) {
            float4 hv = *reinterpret_cast<const float4*>(xr + k4);
            a = fmaf(hv.x, Ws[(k4 + 0) * HID + lane], a);
            a = fmaf(hv.y, Ws[(k4 + 1) * HID + lane], a);
            a = fmaf(hv.z, Ws[(k4 + 2) * HID + lane], a);
            a = fmaf(hv.w, Ws[(k4 + 3) * HID + lane], a);
        }
        out[row * HID + lane] = a;
    }
}

// ---------------- final linear, pass B: out += h1@Wl[128:192] + h2@Wl[192:256] + h3@Wl[256:320]
__global__ __launch_bounds__(256) void k_linB(
        const float* __restrict__ h1, const float* __restrict__ h2,
        const float* __restrict__ h3, const float* __restrict__ Wl,
        float* __restrict__ out) {
    __shared__ float Ws[3 * HID * HID];   // 48 KB
    for (int i = threadIdx.x; i < 3 * HID * HID; i += blockDim.x) Ws[i] = Wl[F_IN * HID + i];
    __syncthreads();
    const int lane = threadIdx.x & 63, rg = threadIdx.x >> 6, rpb = blockDim.x >> 6;
    for (int row = blockIdx.x * rpb + rg; row < N_NODES; row += gridDim.x * rpb) {
        const float* r1 = h1 + (size_t)row * HID;
        const float* r2 = h2 + (size_t)row * HID;
        const float* r3 = h3 + (size_t)row * HID;
        float a = out[row * HID + lane];
        #pragma unroll 8
        for (int k4 = 0; k4 < HID; k4 += 4) {
            float4 v1 = *reinterpret_cast<const float4*>(r1 + k4);
            float4 v2 = *reinterpret_cast<const float4*>(r2 + k4);
            float4 v3 = *reinterpret_cast<const float4*>(r3 + k4);
            a = fmaf(v1.x, Ws[(k4 + 0) * HID + lane], a);
            a = fmaf(v1.y, Ws[(k4 + 1) * HID + lane], a);
            a = fmaf(v1.z, Ws[(k4 + 2) * HID + lane], a);
            a = fmaf(v1.w, Ws[(k4 + 3) * HID + lane], a);
            a = fmaf(v2.x, Ws[(64 + k4 + 0) * HID + lane], a);
            a = fmaf(v2.y, Ws[(64 + k4 + 1) * HID + lane], a);
            a = fmaf(v2.z, Ws[(64 + k4 + 2) * HID + lane], a);
            a = fmaf(v2.w, Ws[(64 + k4 + 3) * HID + lane], a);
            a = fmaf(v3.x, Ws[(128 + k4 + 0) * HID + lane], a);
            a = fmaf(v3.y, Ws[(128 + k4 + 1) * HID + lane], a);
            a = fmaf(v3.z, Ws[(128 + k4 + 2) * HID + lane], a);
            a = fmaf(v3.w, Ws[(128 + k4 + 3) * HID + lane], a);
        }
        out[row * HID + lane] = a;
    }
}

// ---------------- launch ----------------
extern "C" void kernel_launch(void* const* d_in, const int* in_sizes, int n_in,
                              void* d_out, int out_size, void* d_ws, size_t ws_size,
                              hipStream_t stream) {
    const float* x  = (const float*)d_in[0];
    const int*   ei = (const int*)d_in[1];      // edge_index [2, E] int32 (JAX x64 off)
    const float* W0 = (const float*)d_in[2];
    const float* b0 = (const float*)d_in[3];
    const float* W1 = (const float*)d_in[4];
    const float* b1 = (const float*)d_in[5];
    const float* W2 = (const float*)d_in[6];
    const float* b2 = (const float*)d_in[7];
    const float* Wl = (const float*)d_in[8];
    const float* bl = (const float*)d_in[9];
    float* out = (float*)d_out;

    const int* esrc = ei;              // edge_index[0]
    const int* edst = ei + N_EDGES;    // edge_index[1]

    // workspace layout (floats): dis | u | acc | h1 | h2 | h3  = ~128.4 MB
    float* dis = (float*)d_ws;
    float* u   = dis + 102400;
    float* acc = u   + (size_t)N_NODES * HID;
    float* h1  = acc + (size_t)N_NODES * HID;
    float* h2  = h1  + (size_t)N_NODES * HID;
    float* h3  = h2  + (size_t)N_NODES * HID;

    const int nblk_nodes = (N_NODES + 255) / 256;

    k_deg_init<<<nblk_nodes, 256, 0, stream>>>(dis);
    k_deg_accum<<<2048, 256, 0, stream>>>(edst, dis);
    k_dis<<<nblk_nodes, 256, 0, stream>>>(dis);

    // layer 0: x[N,128] -> h1
    k_gemm_scale<F_IN><<<2048, 256, 0, stream>>>(x, W0, dis, u, acc);
    k_scatter<<<4096, 256, 0, stream>>>(esrc, edst, u, acc);
    k_relu<<<2048, 256, 0, stream>>>(acc, dis, b0, h1);

    // layer 1: h1 -> h2
    k_gemm_scale<HID><<<2048, 256, 0, stream>>>(h1, W1, dis, u, acc);
    k_scatter<<<4096, 256, 0, stream>>>(esrc, edst, u, acc);
    k_relu<<<2048, 256, 0, stream>>>(acc, dis, b1, h2);

    // layer 2: h2 -> h3
    k_gemm_scale<HID><<<2048, 256, 0, stream>>>(h2, W2, dis, u, acc);
    k_scatter<<<4096, 256, 0, stream>>>(esrc, edst, u, acc);
    k_relu<<<2048, 256, 0, stream>>>(acc, dis, b2, h3);

    // JK concat + final linear
    k_linA<<<2048, 256, 0, stream>>>(x, Wl, bl, out);
    k_linB<<<2048, 256, 0, stream>>>(h1, h2, h3, Wl, out);
}

// Round 2
// 1033.584 us; speedup vs baseline: 1.7309x; 1.7309x over previous
//
#include <hip/hip_runtime.h>

// GCN 3-layer + JK-concat.  N=100000, E=1600000, F_IN=128, H=64, F_OUT=64.
//
// R1: replace per-edge atomic scatter (400MB HBM atomic writes/layer, 337us x3)
// with per-call CSR build + wave-per-node gather-sum; 8-rows-per-wave register
// blocking in dense kernels (1 LDS read feeds 8 FMAs); relu/bias fused into gather.
//
// Algebra: h_next[d] = relu( dis[d] * ( u[d] + sum_{s->d} u[s] ) + b ),
//          u = (h @ W) * dis[row],  dis = rsqrt(1 + indeg)

#define N_NODES 100000
#define N_EDGES 1600000
#define F_IN    128
#define HID     64
#define NB_SCAN 98          // ceil(N_NODES / 1024)

__global__ void k_zero(int* __restrict__ p, int n) {
    int i = blockIdx.x * blockDim.x + threadIdx.x;
    if (i < n) p[i] = 0;
}

__global__ void k_hist(const int* __restrict__ dst, int* __restrict__ counts) {
    int stride = gridDim.x * blockDim.x;
    for (int e = blockIdx.x * blockDim.x + threadIdx.x; e < N_EDGES; e += stride)
        atomicAdd(&counts[dst[e]], 1);
}

__global__ void k_blocksum(const int* __restrict__ counts, int* __restrict__ blksum) {
    __shared__ int red[256];
    int b = blockIdx.x, t = threadIdx.x;
    int base = b * 1024 + t * 4;
    int s = 0;
    #pragma unroll
    for (int q = 0; q < 4; q++) { int idx = base + q; if (idx < N_NODES) s += counts[idx]; }
    red[t] = s; __syncthreads();
    for (int off = 128; off > 0; off >>= 1) {
        if (t < off) red[t] += red[t + off];
        __syncthreads();
    }
    if (t == 0) blksum[b] = red[0];
}

__global__ void k_scan_top(int* __restrict__ blksum) {   // 1 block, 128 threads
    __shared__ int s[128];
    int t = threadIdx.x;
    s[t] = (t < NB_SCAN) ? blksum[t] : 0;
    __syncthreads();
    for (int off = 1; off < 128; off <<= 1) {
        int v = (t >= off) ? s[t - off] : 0;
        __syncthreads();
        s[t] += v;
        __syncthreads();
    }
    if (t < NB_SCAN) blksum[t] = (t == 0) ? 0 : s[t - 1];   // exclusive
}

__global__ void k_scan_write(const int* __restrict__ counts, const int* __restrict__ blkoff,
                             int* __restrict__ rowptr, int* __restrict__ cursor) {
    __shared__ int ts[256];
    int b = blockIdx.x, t = threadIdx.x;
    int base = b * 1024 + t * 4;
    int c[4]; int s = 0;
    #pragma unroll
    for (int q = 0; q < 4; q++) { int idx = base + q; c[q] = (idx < N_NODES) ? counts[idx] : 0; s += c[q]; }
    ts[t] = s; __syncthreads();
    for (int off = 1; off < 256; off <<= 1) {
        int v = (t >= off) ? ts[t - off] : 0;
        __syncthreads();
        ts[t] += v;
        __syncthreads();
    }
    int run = blkoff[b] + ((t == 0) ? 0 : ts[t - 1]);
    #pragma unroll
    for (int q = 0; q < 4; q++) {
        int idx = base + q;
        if (idx < N_NODES) { rowptr[idx] = run; cursor[idx] = run; run += c[q]; }
    }
}

__global__ void k_dis_from_counts(const int* __restrict__ counts, float* __restrict__ dis,
                                  int* __restrict__ rowptr) {
    int i = blockIdx.x * blockDim.x + threadIdx.x;
    if (i < N_NODES) dis[i] = rsqrtf(1.0f + (float)counts[i]);
    if (i == 0) rowptr[N_NODES] = N_EDGES;
}

__global__ void k_place(const int* __restrict__ src, const int* __restrict__ dst,
                        int* __restrict__ cursor, int* __restrict__ esorted) {
    int stride = gridDim.x * blockDim.x;
    for (int e = blockIdx.x * blockDim.x + threadIdx.x; e < N_EDGES; e += stride) {
        int d = dst[e];
        int pos = atomicAdd(&cursor[d], 1);
        esorted[pos] = src[e];
    }
}

// u = (h @ W) * dis[row],  8 rows per wave
template<int K>
__global__ __launch_bounds__(256) void k_gemm_scale(
        const float* __restrict__ h, const float* __restrict__ W,
        const float* __restrict__ dis, float* __restrict__ u) {
    __shared__ float Ws[K * HID];
    for (int i = threadIdx.x; i < K * HID; i += blockDim.x) Ws[i] = W[i];
    __syncthreads();
    const int lane = threadIdx.x & 63, wid = threadIdx.x >> 6, wpb = blockDim.x >> 6;
    const int ngrp = N_NODES / 8;   // 12500, exact
    for (int g = blockIdx.x * wpb + wid; g < ngrp; g += gridDim.x * wpb) {
        const int r0 = g * 8;
        const float* hr = h + (size_t)r0 * K;
        float acc[8] = {0.f, 0.f, 0.f, 0.f, 0.f, 0.f, 0.f, 0.f};
        for (int k4 = 0; k4 < K; k4 += 4) {
            float4 hv[8];
            #pragma unroll
            for (int r = 0; r < 8; r++)
                hv[r] = *reinterpret_cast<const float4*>(hr + (size_t)r * K + k4);
            float w0 = Ws[(k4 + 0) * HID + lane];
            float w1 = Ws[(k4 + 1) * HID + lane];
            float w2 = Ws[(k4 + 2) * HID + lane];
            float w3 = Ws[(k4 + 3) * HID + lane];
            #pragma unroll
            for (int r = 0; r < 8; r++) {
                acc[r] = fmaf(hv[r].x, w0, acc[r]);
                acc[r] = fmaf(hv[r].y, w1, acc[r]);
                acc[r] = fmaf(hv[r].z, w2, acc[r]);
                acc[r] = fmaf(hv[r].w, w3, acc[r]);
            }
        }
        #pragma unroll
        for (int r = 0; r < 8; r++)
            u[(size_t)(r0 + r) * HID + lane] = acc[r] * dis[r0 + r];
    }
}

// h = relu(dis[d]*(u[d]+sum u[s]) + b), wave per node
__global__ __launch_bounds__(256) void k_gather_relu(
        const int* __restrict__ rowptr, const int* __restrict__ es,
        const float* __restrict__ u, const float* __restrict__ dis,
        const float* __restrict__ bias, float* __restrict__ hout) {
    const int lane = threadIdx.x & 63, wid = threadIdx.x >> 6, wpb = blockDim.x >> 6;
    const float bj = bias[lane];
    for (int d = blockIdx.x * wpb + wid; d < N_NODES; d += gridDim.x * wpb) {
        float a = u[(size_t)d * HID + lane];          // self loop
        int i = rowptr[d], end = rowptr[d + 1];
        for (; i + 4 <= end; i += 4) {
            int s0 = es[i], s1 = es[i + 1], s2 = es[i + 2], s3 = es[i + 3];
            float v0 = u[(size_t)s0 * HID + lane];
            float v1 = u[(size_t)s1 * HID + lane];
            float v2 = u[(size_t)s2 * HID + lane];
            float v3 = u[(size_t)s3 * HID + lane];
            a += v0; a += v1; a += v2; a += v3;
        }
        for (; i < end; i++) a += u[(size_t)es[i] * HID + lane];
        float v = fmaf(a, dis[d], bj);
        hout[(size_t)d * HID + lane] = v > 0.f ? v : 0.f;
    }
}

// out = bl + x @ Wl[0:128], 8 rows/wave
__global__ __launch_bounds__(256) void k_linA(
        const float* __restrict__ x, const float* __restrict__ Wl,
        const float* __restrict__ bl, float* __restrict__ out) {
    __shared__ float Ws[F_IN * HID];   // 32 KB
    for (int i = threadIdx.x; i < F_IN * HID; i += blockDim.x) Ws[i] = Wl[i];
    __syncthreads();
    const int lane = threadIdx.x & 63, wid = threadIdx.x >> 6, wpb = blockDim.x >> 6;
    const float bj = bl[lane];
    const int ngrp = N_NODES / 8;
    for (int g = blockIdx.x * wpb + wid; g < ngrp; g += gridDim.x * wpb) {
        const int r0 = g * 8;
        const float* xr = x + (size_t)r0 * F_IN;
        float acc[8] = {bj, bj, bj, bj, bj, bj, bj, bj};
        for (int k4 = 0; k4 < F_IN; k4 += 4) {
            float4 hv[8];
            #pragma unroll
            for (int r = 0; r < 8; r++)
                hv[r] = *reinterpret_cast<const float4*>(xr + (size_t)r * F_IN + k4);
            float w0 = Ws[(k4 + 0) * HID + lane];
            float w1 = Ws[(k4 + 1) * HID + lane];
            float w2 = Ws[(k4 + 2) * HID + lane];
            float w3 = Ws[(k4 + 3) * HID + lane];
            #pragma unroll
            for (int r = 0; r < 8; r++) {
                acc[r] = fmaf(hv[r].x, w0, acc[r]);
                acc[r] = fmaf(hv[r].y, w1, acc[r]);
                acc[r] = fmaf(hv[r].z, w2, acc[r]);
                acc[r] = fmaf(hv[r].w, w3, acc[r]);
            }
        }
        #pragma unroll
        for (int r = 0; r < 8; r++)
            out[(size_t)(r0 + r) * HID + lane] = acc[r];
    }
}

// out += [h1|h2|h3] @ Wl[128:320], 8 rows/wave
__global__ __launch_bounds__(256) void k_linB(
        const float* __restrict__ h1, const float* __restrict__ h2,
        const float* __restrict__ h3, const float* __restrict__ Wl,
        float* __restrict__ out) {
    __shared__ float Ws[3 * HID * HID];   // 48 KB
    for (int i = threadIdx.x; i < 3 * HID * HID; i += blockDim.x) Ws[i] = Wl[F_IN * HID + i];
    __syncthreads();
    const int lane = threadIdx.x & 63, wid = threadIdx.x >> 6, wpb = blockDim.x >> 6;
    const int ngrp = N_NODES / 8;
    for (int g = blockIdx.x * wpb + wid; g < ngrp; g += gridDim.x * wpb) {
        const int r0 = g * 8;
        float acc[8];
        #pragma unroll
        for (int r = 0; r < 8; r++) acc[r] = out[(size_t)(r0 + r) * HID + lane];
        #pragma unroll
        for (int sgi = 0; sgi < 3; sgi++) {
            const float* hr = (sgi == 0 ? h1 : sgi == 1 ? h2 : h3) + (size_t)r0 * HID;
            const float* Wseg = Ws + sgi * HID * HID;
            for (int k4 = 0; k4 < HID; k4 += 4) {
                float4 hv[8];
                #pragma unroll
                for (int r = 0; r < 8; r++)
                    hv[r] = *reinterpret_cast<const float4*>(hr + (size_t)r * HID + k4);
                float w0 = Wseg[(k4 + 0) * HID + lane];
                float w1 = Wseg[(k4 + 1) * HID + lane];
                float w2 = Wseg[(k4 + 2) * HID + lane];
                float w3 = Wseg[(k4 + 3) * HID + lane];
                #pragma unroll
                for (int r = 0; r < 8; r++) {
                    acc[r] = fmaf(hv[r].x, w0, acc[r]);
                    acc[r] = fmaf(hv[r].y, w1, acc[r]);
                    acc[r] = fmaf(hv[r].z, w2, acc[r]);
                    acc[r] = fmaf(hv[r].w, w3, acc[r]);
                }
            }
        }
        #pragma unroll
        for (int r = 0; r < 8; r++)
            out[(size_t)(r0 + r) * HID + lane] = acc[r];
    }
}

extern "C" void kernel_launch(void* const* d_in, const int* in_sizes, int n_in,
                              void* d_out, int out_size, void* d_ws, size_t ws_size,
                              hipStream_t stream) {
    const float* x  = (const float*)d_in[0];
    const int*   ei = (const int*)d_in[1];      // edge_index [2, E] int32
    const float* W0 = (const float*)d_in[2];
    const float* b0 = (const float*)d_in[3];
    const float* W1 = (const float*)d_in[4];
    const float* b1 = (const float*)d_in[5];
    const float* W2 = (const float*)d_in[6];
    const float* b2 = (const float*)d_in[7];
    const float* Wl = (const float*)d_in[8];
    const float* bl = (const float*)d_in[9];
    float* out = (float*)d_out;

    const int* esrc = ei;
    const int* edst = ei + N_EDGES;

    // workspace layout (byte offsets; total ~110.5 MB)
    char* w = (char*)d_ws;
    float* dis     = (float*)(w);                       //   409,600 B
    float* u       = (float*)(w + 409600);              // 25,600,000
    float* h1      = (float*)(w + 26009600);            // 25,600,000
    float* h2      = (float*)(w + 51609600);            // 25,600,000
    float* h3      = (float*)(w + 77209600);            // 25,600,000
    int*   counts  = (int*)  (w + 102809600);           //    409,600
    int*   rowptr  = (int*)  (w + 103219200);           //    409,600 (N+1)
    int*   cursor  = (int*)  (w + 103628800);           //    409,600
    int*   esorted = (int*)  (w + 104038400);           //  6,400,000
    int*   blksum  = (int*)  (w + 110438400);           //        512

    const int nblk_nodes = (N_NODES + 255) / 256;

    // CSR build (ws re-poisoned each call, so rebuild every time)
    k_zero<<<nblk_nodes, 256, 0, stream>>>(counts, N_NODES);
    k_hist<<<2048, 256, 0, stream>>>(edst, counts);
    k_blocksum<<<NB_SCAN, 256, 0, stream>>>(counts, blksum);
    k_scan_top<<<1, 128, 0, stream>>>(blksum);
    k_scan_write<<<NB_SCAN, 256, 0, stream>>>(counts, blksum, rowptr, cursor);
    k_dis_from_counts<<<nblk_nodes, 256, 0, stream>>>(counts, dis, rowptr);
    k_place<<<2048, 256, 0, stream>>>(esrc, edst, cursor, esorted);

    // layer 0
    k_gemm_scale<F_IN><<<1024, 256, 0, stream>>>(x, W0, dis, u);
    k_gather_relu<<<2048, 256, 0, stream>>>(rowptr, esorted, u, dis, b0, h1);
    // layer 1
    k_gemm_scale<HID><<<1024, 256, 0, stream>>>(h1, W1, dis, u);
    k_gather_relu<<<2048, 256, 0, stream>>>(rowptr, esorted, u, dis, b1, h2);
    // layer 2
    k_gemm_scale<HID><<<1024, 256, 0, stream>>>(h2, W2, dis, u);
    k_gather_relu<<<2048, 256, 0, stream>>>(rowptr, esorted, u, dis, b2, h3);

    // JK concat + final linear
    k_linA<<<1024, 256, 0, stream>>>(x, Wl, bl, out);
    k_linB<<<1024, 256, 0, stream>>>(h1, h2, h3, Wl, out);
}

// Round 6
// 751.616 us; speedup vs baseline: 2.3802x; 1.3751x over previous
//
#include <hip/hip_runtime.h>

// GCN 3-layer + JK-concat.  N=100000, E=1600000, F_IN=128, H=64, F_OUT=64.
//
// R2 (resubmitted R3-R5 across infra failures; audited for crash surfaces:
// no OOB, ws high-water identical to the R1 layout that passed, no capture
// violations): dense kernels restructured lane=row. R1's dense kernels loaded
// row data at wave-UNIFORM addresses -> compiler scalarized streamed X through
// the tiny scalar cache (k_linB 210us, VALUBusy 16%, latency-bound). Now: X
// rows are per-lane VECTOR loads into registers; the wave-shared operand is
// W[k][j] (small, hot, reused) which rides the scalar path for free. 64 FMAs
// per k-step with ~zero overhead ops -> near f32-VALU roofline.
//
// Algebra: h_next[d] = relu( dis[d] * ( u[d] + sum_{s->d} u[s] ) + b ),
//          u = (h @ W) * dis[row],  dis = rsqrt(1 + indeg)

#define N_NODES 100000
#define N_EDGES 1600000
#define F_IN    128
#define HID     64
#define NB_SCAN 98          // ceil(N_NODES / 1024)

// ================= CSR build =================
__global__ void k_zero(int* __restrict__ p, int n) {
    int i = blockIdx.x * blockDim.x + threadIdx.x;
    if (i < n) p[i] = 0;
}

__global__ void k_hist(const int* __restrict__ dst, int* __restrict__ counts) {
    int stride = gridDim.x * blockDim.x;
    for (int e = blockIdx.x * blockDim.x + threadIdx.x; e < N_EDGES; e += stride)
        atomicAdd(&counts[dst[e]], 1);
}

__global__ void k_blocksum(const int* __restrict__ counts, int* __restrict__ blksum) {
    __shared__ int red[256];
    int b = blockIdx.x, t = threadIdx.x;
    int base = b * 1024 + t * 4;
    int s = 0;
    #pragma unroll
    for (int q = 0; q < 4; q++) { int idx = base + q; if (idx < N_NODES) s += counts[idx]; }
    red[t] = s; __syncthreads();
    for (int off = 128; off > 0; off >>= 1) {
        if (t < off) red[t] += red[t + off];
        __syncthreads();
    }
    if (t == 0) blksum[b] = red[0];
}

__global__ void k_scan_top(int* __restrict__ blksum) {   // 1 block, 128 threads
    __shared__ int s[128];
    int t = threadIdx.x;
    s[t] = (t < NB_SCAN) ? blksum[t] : 0;
    __syncthreads();
    for (int off = 1; off < 128; off <<= 1) {
        int v = (t >= off) ? s[t - off] : 0;
        __syncthreads();
        s[t] += v;
        __syncthreads();
    }
    if (t < NB_SCAN) blksum[t] = (t == 0) ? 0 : s[t - 1];   // exclusive
}

__global__ void k_scan_write(const int* __restrict__ counts, const int* __restrict__ blkoff,
                             int* __restrict__ rowptr, int* __restrict__ cursor) {
    __shared__ int ts[256];
    int b = blockIdx.x, t = threadIdx.x;
    int base = b * 1024 + t * 4;
    int c[4]; int s = 0;
    #pragma unroll
    for (int q = 0; q < 4; q++) { int idx = base + q; c[q] = (idx < N_NODES) ? counts[idx] : 0; s += c[q]; }
    ts[t] = s; __syncthreads();
    for (int off = 1; off < 256; off <<= 1) {
        int v = (t >= off) ? ts[t - off] : 0;
        __syncthreads();
        ts[t] += v;
        __syncthreads();
    }
    int run = blkoff[b] + ((t == 0) ? 0 : ts[t - 1]);
    #pragma unroll
    for (int q = 0; q < 4; q++) {
        int idx = base + q;
        if (idx < N_NODES) { rowptr[idx] = run; cursor[idx] = run; run += c[q]; }
    }
}

__global__ void k_dis_from_counts(const int* __restrict__ counts, float* __restrict__ dis,
                                  int* __restrict__ rowptr) {
    int i = blockIdx.x * blockDim.x + threadIdx.x;
    if (i < N_NODES) dis[i] = rsqrtf(1.0f + (float)counts[i]);
    if (i == 0) rowptr[N_NODES] = N_EDGES;
}

__global__ void k_place(const int* __restrict__ src, const int* __restrict__ dst,
                        int* __restrict__ cursor, int* __restrict__ esorted) {
    int stride = gridDim.x * blockDim.x;
    for (int e = blockIdx.x * blockDim.x + threadIdx.x; e < N_EDGES; e += stride) {
        int d = dst[e];
        int pos = atomicAdd(&cursor[d], 1);
        esorted[pos] = src[e];
    }
}

// ================= dense: lane = row, W via scalar path =================
// Accumulate acc[j] += X[row][k] * W[k][j] over k in [0,K). xr is lane's row.
template<int K>
__device__ __forceinline__ void seg_accum(const float* __restrict__ xr,
                                          const float* __restrict__ W,
                                          float (&acc)[64]) {
    #pragma unroll 1
    for (int k0 = 0; k0 < K; k0 += 16) {
        float xb[16];
        #pragma unroll
        for (int q = 0; q < 4; q++) {
            float4 v = *reinterpret_cast<const float4*>(xr + k0 + 4 * q);
            xb[4 * q + 0] = v.x; xb[4 * q + 1] = v.y;
            xb[4 * q + 2] = v.z; xb[4 * q + 3] = v.w;
        }
        #pragma unroll
        for (int kk = 0; kk < 16; kk++) {
            const float* wk = W + (size_t)(k0 + kk) * 64;   // wave-uniform -> s_load
            #pragma unroll
            for (int j = 0; j < 64; j++)
                acc[j] = fmaf(xb[kk], wk[j], acc[j]);
        }
    }
}

// u[r][:] = (X[r][:] @ W) * dis[r]
template<int K>
__global__ __launch_bounds__(256, 4) void k_rowgemm(
        const float* __restrict__ X, const float* __restrict__ W,
        const float* __restrict__ dis, float* __restrict__ u) {
    const int lane   = threadIdx.x & 63;
    const int wid    = blockIdx.x * (blockDim.x >> 6) + (threadIdx.x >> 6);
    const int nwaves = gridDim.x * (blockDim.x >> 6);
    const int ntiles = (N_NODES + 63) / 64;
    for (int tile = wid; tile < ntiles; tile += nwaves) {
        int r  = tile * 64 + lane;
        int rc = r < N_NODES ? r : N_NODES - 1;
        const float* xr = X + (size_t)rc * K;
        float acc[64];
        #pragma unroll
        for (int j = 0; j < 64; j++) acc[j] = 0.f;
        seg_accum<K>(xr, W, acc);
        if (r < N_NODES) {
            float dv = dis[r];
            float* orow = u + (size_t)r * 64;
            #pragma unroll
            for (int j4 = 0; j4 < 16; j4++) {
                float4 st = { acc[4*j4] * dv, acc[4*j4+1] * dv,
                              acc[4*j4+2] * dv, acc[4*j4+3] * dv };
                *reinterpret_cast<float4*>(orow + 4 * j4) = st;
            }
        }
    }
}

// out[r][:] = bl + x[r]@Wl[0:128] + h1[r]@Wl[128:192] + h2[r]@Wl[192:256] + h3[r]@Wl[256:320]
__global__ __launch_bounds__(256, 4) void k_linfused(
        const float* __restrict__ x,  const float* __restrict__ h1,
        const float* __restrict__ h2, const float* __restrict__ h3,
        const float* __restrict__ Wl, const float* __restrict__ bl,
        float* __restrict__ out) {
    const int lane   = threadIdx.x & 63;
    const int wid    = blockIdx.x * (blockDim.x >> 6) + (threadIdx.x >> 6);
    const int nwaves = gridDim.x * (blockDim.x >> 6);
    const int ntiles = (N_NODES + 63) / 64;
    for (int tile = wid; tile < ntiles; tile += nwaves) {
        int r  = tile * 64 + lane;
        int rc = r < N_NODES ? r : N_NODES - 1;
        float acc[64];
        #pragma unroll
        for (int j = 0; j < 64; j++) acc[j] = bl[j];     // uniform -> s_load
        seg_accum<F_IN>(x  + (size_t)rc * F_IN, Wl,                  acc);
        seg_accum<HID >(h1 + (size_t)rc * HID,  Wl + 128 * 64,       acc);
        seg_accum<HID >(h2 + (size_t)rc * HID,  Wl + 192 * 64,       acc);
        seg_accum<HID >(h3 + (size_t)rc * HID,  Wl + 256 * 64,       acc);
        if (r < N_NODES) {
            float* orow = out + (size_t)r * 64;
            #pragma unroll
            for (int j4 = 0; j4 < 16; j4++) {
                float4 st = { acc[4*j4], acc[4*j4+1], acc[4*j4+2], acc[4*j4+3] };
                *reinterpret_cast<float4*>(orow + 4 * j4) = st;
            }
        }
    }
}

// ================= gather: h = relu(dis[d]*(u[d]+sum u[s]) + b) =================
__global__ __launch_bounds__(256) void k_gather_relu(
        const int* __restrict__ rowptr, const int* __restrict__ es,
        const float* __restrict__ u, const float* __restrict__ dis,
        const float* __restrict__ bias, float* __restrict__ hout) {
    const int lane = threadIdx.x & 63, wid = threadIdx.x >> 6, wpb = blockDim.x >> 6;
    const float bj = bias[lane];
    for (int d = blockIdx.x * wpb + wid; d < N_NODES; d += gridDim.x * wpb) {
        float a = u[(size_t)d * HID + lane];          // self loop
        int i = rowptr[d], end = rowptr[d + 1];
        for (; i + 4 <= end; i += 4) {
            int s0 = es[i], s1 = es[i + 1], s2 = es[i + 2], s3 = es[i + 3];
            float v0 = u[(size_t)s0 * HID + lane];
            float v1 = u[(size_t)s1 * HID + lane];
            float v2 = u[(size_t)s2 * HID + lane];
            float v3 = u[(size_t)s3 * HID + lane];
            a += v0; a += v1; a += v2; a += v3;
        }
        for (; i < end; i++) a += u[(size_t)es[i] * HID + lane];
        float v = fmaf(a, dis[d], bj);
        hout[(size_t)d * HID + lane] = v > 0.f ? v : 0.f;
    }
}

// ================= launch =================
extern "C" void kernel_launch(void* const* d_in, const int* in_sizes, int n_in,
                              void* d_out, int out_size, void* d_ws, size_t ws_size,
                              hipStream_t stream) {
    const float* x  = (const float*)d_in[0];
    const int*   ei = (const int*)d_in[1];      // edge_index [2, E] int32
    const float* W0 = (const float*)d_in[2];
    const float* b0 = (const float*)d_in[3];
    const float* W1 = (const float*)d_in[4];
    const float* b1 = (const float*)d_in[5];
    const float* W2 = (const float*)d_in[6];
    const float* b2 = (const float*)d_in[7];
    const float* Wl = (const float*)d_in[8];
    const float* bl = (const float*)d_in[9];
    float* out = (float*)d_out;

    const int* esrc = ei;
    const int* edst = ei + N_EDGES;

    // workspace layout (byte offsets; total ~110.5 MB)
    char* w = (char*)d_ws;
    float* dis     = (float*)(w);                       //   409,600 B
    float* u       = (float*)(w + 409600);              // 25,600,000
    float* h1      = (float*)(w + 26009600);            // 25,600,000
    float* h2      = (float*)(w + 51609600);            // 25,600,000
    float* h3      = (float*)(w + 77209600);            // 25,600,000
    int*   counts  = (int*)  (w + 102809600);           //    409,600
    int*   rowptr  = (int*)  (w + 103219200);           //    409,600 (N+1)
    int*   cursor  = (int*)  (w + 103628800);           //    409,600
    int*   esorted = (int*)  (w + 104038400);           //  6,400,000
    int*   blksum  = (int*)  (w + 110438400);           //        512

    const int nblk_nodes = (N_NODES + 255) / 256;
    const int GB = 391;   // ceil(1563 row-tiles / 4 waves-per-block)

    // CSR build (ws re-poisoned each call, so rebuild every time)
    k_zero<<<nblk_nodes, 256, 0, stream>>>(counts, N_NODES);
    k_hist<<<2048, 256, 0, stream>>>(edst, counts);
    k_blocksum<<<NB_SCAN, 256, 0, stream>>>(counts, blksum);
    k_scan_top<<<1, 128, 0, stream>>>(blksum);
    k_scan_write<<<NB_SCAN, 256, 0, stream>>>(counts, blksum, rowptr, cursor);
    k_dis_from_counts<<<nblk_nodes, 256, 0, stream>>>(counts, dis, rowptr);
    k_place<<<2048, 256, 0, stream>>>(esrc, edst, cursor, esorted);

    // layer 0
    k_rowgemm<F_IN><<<GB, 256, 0, stream>>>(x, W0, dis, u);
    k_gather_relu<<<2048, 256, 0, stream>>>(rowptr, esorted, u, dis, b0, h1);
    // layer 1
    k_rowgemm<HID><<<GB, 256, 0, stream>>>(h1, W1, dis, u);
    k_gather_relu<<<2048, 256, 0, stream>>>(rowptr, esorted, u, dis, b1, h2);
    // layer 2
    k_rowgemm<HID><<<GB, 256, 0, stream>>>(h2, W2, dis, u);
    k_gather_relu<<<2048, 256, 0, stream>>>(rowptr, esorted, u, dis, b2, h3);

    // JK concat + final linear (fused)
    k_linfused<<<GB, 256, 0, stream>>>(x, h1, h2, h3, Wl, bl, out);
}